// Round 1
// baseline (994.733 us; speedup 1.0000x reference)
//
#include <hip/hip_runtime.h>
#include <hip/hip_bf16.h>

// Problem constants (from reference)
#define TB   8192   // B*C*N bags
#define WW   32     // words per bag
#define DD   512    // d_model
#define DKK  64     // attention dim
#define CCC  4      // max cross
#define NNN  32     // max nodes

#define BAG_STRIDE 520  // shorts per LDS bag row (512 + 8 pad -> 4-bank shift per row)

__device__ __forceinline__ float bf2f(unsigned s) {
    union { unsigned u; float f; } u;
    u.u = s << 16;
    return u.f;
}
__device__ __forceinline__ unsigned f2bf(float x) {
    union { float f; unsigned u; } u;
    u.f = x;
    unsigned r = u.u + 0x7fffu + ((u.u >> 16) & 1u);
    return r >> 16;
}

// Kernel A: q[b,k] = dot(con_hidden[b,:], W_q[:,k]); also copy hidden to output.
__global__ __launch_bounds__(64) void prep_kernel(
    const float* __restrict__ con_hidden,  // [64][512]
    const float* __restrict__ W_q,         // [512][64]
    float* __restrict__ qout,              // [64][64]
    float* __restrict__ hid_out)           // [64][512]
{
    const int b = blockIdx.x;
    const int k = threadIdx.x;  // 0..63
    const float* h = con_hidden + b * DD;
    float acc = 0.0f;
    #pragma unroll 8
    for (int d = 0; d < DD; ++d) {
        acc += h[d] * W_q[d * DKK + k];   // h[d] broadcast, W_q coalesced
    }
    qout[b * DKK + k] = acc;
    // copy hidden row (512 floats) as float4
    const float4* src = (const float4*)h;
    float4* dst = (float4*)(hid_out + b * DD);
    for (int i = k; i < DD / 4; i += 64) dst[i] = src[i];
}

// Kernel B: one block per bag. gather -> pre GEMM -> energy -> softmax -> context -> out
__global__ __launch_bounds__(256) void bag_kernel(
    const int* __restrict__ token_ids,     // [8192][32]
    const int* __restrict__ node_lengths,  // [8192]
    const int* __restrict__ node_sizes,    // [256]
    const int* __restrict__ cross_lengths, // [64]
    const float* __restrict__ emb,         // [32000][512]
    const float* __restrict__ W_pre,       // [512][64]
    const float* __restrict__ b_pre,       // [64]
    const float* __restrict__ v,           // [64]
    const float* __restrict__ q,           // [64][64]
    float* __restrict__ out)               // [8192][512]
{
    const int t   = blockIdx.x;
    const int tid = threadIdx.x;
    const int b   = t >> 7;        // / (C*N) = /128
    const int cn  = t & 127;
    const int c   = cn >> 5;
    const int n   = cn & 31;

    __shared__ unsigned short bag[WW][BAG_STRIDE];  // bf16, 33280 B
    __shared__ float sh_q[DKK];
    __shared__ float sh_e[WW];
    __shared__ float sh_score[WW];

    const int L = node_lengths[t];
    const int* toks = token_ids + t * WW;

    // ---- gather: each thread loads 2 consecutive floats of each row ----
    const int d0 = tid * 2;  // 0..510
    for (int w = 0; w < WW; ++w) {
        unsigned packed = 0u;
        if (w < L) {                                   // wave-uniform branch
            const float* row = emb + (size_t)toks[w] * DD;
            float2 val = *(const float2*)(row + d0);
            packed = f2bf(val.x) | (f2bf(val.y) << 16);
        }
        *(unsigned*)&bag[w][d0] = packed;
    }
    if (tid < DKK) sh_q[tid] = q[b * DKK + tid];
    __syncthreads();

    // ---- pre GEMM + energy: thread -> (w = tid>>3, k0 = (tid&7)*8) ----
    {
        const int w  = tid >> 3;
        const int k0 = (tid & 7) * 8;
        float acc[8];
        #pragma unroll
        for (int i = 0; i < 8; ++i) acc[i] = 0.0f;

        for (int d = 0; d < DD; d += 2) {
            unsigned pk = *(const unsigned*)&bag[w][d];
            float a0 = bf2f(pk & 0xffffu);
            float a1 = bf2f(pk >> 16);
            const float4* wp0 = (const float4*)(W_pre + d * DKK + k0);
            const float4* wp1 = (const float4*)(W_pre + (d + 1) * DKK + k0);
            float4 w00 = wp0[0], w01 = wp0[1];
            float4 w10 = wp1[0], w11 = wp1[1];
            acc[0] += a0 * w00.x; acc[1] += a0 * w00.y;
            acc[2] += a0 * w00.z; acc[3] += a0 * w00.w;
            acc[4] += a0 * w01.x; acc[5] += a0 * w01.y;
            acc[6] += a0 * w01.z; acc[7] += a0 * w01.w;
            acc[0] += a1 * w10.x; acc[1] += a1 * w10.y;
            acc[2] += a1 * w10.z; acc[3] += a1 * w10.w;
            acc[4] += a1 * w11.x; acc[5] += a1 * w11.y;
            acc[6] += a1 * w11.z; acc[7] += a1 * w11.w;
        }
        // energy partial over this thread's 8 k's
        float ep = 0.0f;
        #pragma unroll
        for (int i = 0; i < 8; ++i) {
            int k = k0 + i;
            float pre = acc[i] + b_pre[k] + sh_q[k];
            ep += tanhf(pre) * v[k];
        }
        // reduce across the 8 lanes sharing w (consecutive lanes in wave)
        ep += __shfl_xor(ep, 1);
        ep += __shfl_xor(ep, 2);
        ep += __shfl_xor(ep, 4);
        if ((tid & 7) == 0) sh_e[w] = ep;
    }
    __syncthreads();

    // ---- softmax over all 32 word slots (matches reference: no length mask) ----
    if (tid < 32) {
        float e = sh_e[tid];
        float mx = e;
        #pragma unroll
        for (int s = 16; s; s >>= 1) mx = fmaxf(mx, __shfl_xor(mx, s));
        float ex = expf(e - mx);
        float sm = ex;
        #pragma unroll
        for (int s = 16; s; s >>= 1) sm += __shfl_xor(sm, s);
        sh_score[tid] = ex / sm;
    }
    __syncthreads();

    // ---- context: each thread owns 2 consecutive d's ----
    float c0 = 0.0f, c1 = 0.0f;
    #pragma unroll 8
    for (int w2 = 0; w2 < WW; ++w2) {
        unsigned pk = *(const unsigned*)&bag[w2][d0];
        float s = sh_score[w2];
        c0 += s * bf2f(pk & 0xffffu);
        c1 += s * bf2f(pk >> 16);
    }
    const bool outmask = (n < node_sizes[b * CCC + c]) && (c < cross_lengths[b]);
    if (!outmask) { c0 = 0.0f; c1 = 0.0f; }
    float2 o; o.x = c0; o.y = c1;
    *(float2*)(out + (size_t)t * DD + d0) = o;
}

extern "C" void kernel_launch(void* const* d_in, const int* in_sizes, int n_in,
                              void* d_out, int out_size, void* d_ws, size_t ws_size,
                              hipStream_t stream) {
    const int*   token_ids     = (const int*)d_in[0];
    const int*   node_lengths  = (const int*)d_in[1];
    const int*   node_sizes    = (const int*)d_in[2];
    const int*   cross_lengths = (const int*)d_in[3];
    const float* con_hidden    = (const float*)d_in[4];
    const float* emb           = (const float*)d_in[5];
    const float* W_pre         = (const float*)d_in[6];
    const float* b_pre         = (const float*)d_in[7];
    const float* W_q           = (const float*)d_in[8];
    const float* v             = (const float*)d_in[9];

    float* out     = (float*)d_out;
    float* hid_out = out + (size_t)TB * DD;   // second output, offset 4194304
    float* q       = (float*)d_ws;            // 64*64 floats = 16 KB scratch

    prep_kernel<<<64, 64, 0, stream>>>(con_hidden, W_q, q, hid_out);
    bag_kernel<<<TB, 256, 0, stream>>>(token_ids, node_lengths, node_sizes,
                                       cross_lengths, emb, W_pre, b_pre, v, q, out);
}

// Round 3
// 126.478 us; speedup vs baseline: 7.8649x; 7.8649x over previous
//
#include <hip/hip_runtime.h>
#include <hip/hip_bf16.h>

#define TB   8192   // B*C*N bags
#define WW   32     // words per bag
#define DD   512    // d_model
#define DKK  64     // attention dim
#define CCC  4      // max cross

using bf16x8 = __attribute__((ext_vector_type(8))) short;
using f32x4  = __attribute__((ext_vector_type(4))) float;

__device__ __forceinline__ unsigned short f2bf(float x) {
    union { float f; unsigned u; } u;
    u.f = x;
    unsigned r = u.u + 0x7fffu + ((u.u >> 16) & 1u);
    return (unsigned short)(r >> 16);
}

// pack two float4 (8 consecutive fp32) into one bf16x8 fragment (RNE)
__device__ __forceinline__ bf16x8 make_frag(float4 x, float4 y) {
    union { bf16x8 v; __hip_bfloat162 h[4]; } u;
    u.h[0] = __float22bfloat162_rn(float2{x.x, x.y});
    u.h[1] = __float22bfloat162_rn(float2{x.z, x.w});
    u.h[2] = __float22bfloat162_rn(float2{y.x, y.y});
    u.h[3] = __float22bfloat162_rn(float2{y.z, y.w});
    return u.v;
}

// Kernel A: q[b,k] = dot(con_hidden[b,:], W_q[:,k]); copy hidden to output 2.
__global__ __launch_bounds__(64) void prep_kernel(
    const float* __restrict__ con_hidden,  // [64][512]
    const float* __restrict__ W_q,         // [512][64]
    float* __restrict__ qout,              // [64][64]
    float* __restrict__ hid_out)           // [64][512]
{
    const int b = blockIdx.x;
    const int k = threadIdx.x;  // 0..63
    const float* h = con_hidden + b * DD;
    float acc = 0.0f;
    #pragma unroll 8
    for (int d = 0; d < DD; ++d) acc += h[d] * W_q[d * DKK + k];
    qout[b * DKK + k] = acc;
    const float4* src = (const float4*)h;
    float4* dst = (float4*)(hid_out + b * DD);
    for (int i = k; i < DD / 4; i += 64) dst[i] = src[i];
}

// Kernel B: pack W_pre (512x64 fp32) into B-fragment-major bf16.
// frag (ks, nt): lane l holds W_pre[ks*32 + (l>>4)*8 + j][nt*16 + (l&15)], j=0..7
__global__ __launch_bounds__(64) void pack_wpre(
    const float* __restrict__ W_pre,
    bf16x8* __restrict__ wb)               // 64 frags * 64 lanes * 16B = 64 KB
{
    const int blk = blockIdx.x;            // ks*4 + nt  (64 blocks)
    const int ks = blk >> 2, nt = blk & 3;
    const int l  = threadIdx.x;
    const int lr = l & 15, lg = l >> 4;
    union { bf16x8 v; unsigned short s[8]; } u;
    #pragma unroll
    for (int j = 0; j < 8; ++j) {
        int k = ks * 32 + lg * 8 + j;
        u.s[j] = f2bf(W_pre[k * DKK + nt * 16 + lr]);
    }
    wb[blk * 64 + l] = u.v;
}

// Kernel C: one WAVE per bag. MFMA pre-GEMM -> energy -> softmax -> context.
__global__ __launch_bounds__(256) void bag_kernel(
    const int* __restrict__ token_ids,     // [8192][32]
    const int* __restrict__ node_lengths,  // [8192]
    const int* __restrict__ node_sizes,    // [256]
    const int* __restrict__ cross_lengths, // [64]
    const float* __restrict__ emb,         // [32000][512], row 0 is zeros
    const float* __restrict__ b_pre,       // [64]
    const float* __restrict__ v,           // [64]
    const float* __restrict__ q,           // [64][64]
    const bf16x8* __restrict__ wb,         // packed W_pre fragments
    float* __restrict__ out)               // [8192][512]
{
    const int wid  = threadIdx.x >> 6;
    const int lane = threadIdx.x & 63;
    const int t = blockIdx.x * 4 + wid;
    const int b = t >> 7, cn = t & 127, c = cn >> 5, n = cn & 31;
    const int lr = lane & 15, lg = lane >> 4;

    __shared__ int   sh_tok[4][32];
    __shared__ float sh_e[4][32];
    __shared__ float sh_s[4][32];

    const int L = node_lengths[t];
    const int* toks = token_ids + t * WW;

    // stash masked token ids for the context phase (emb[0] is all-zero)
    if (lane < 32) {
        int tok = toks[lane];
        sh_tok[wid][lane] = (lane < L) ? tok : 0;
    }

    // per-lane A-row pointers for the two M-tiles (words lr and 16+lr)
    const int w1 = 16 + lr;
    const int tok0 = (lr < L) ? toks[lr] : 0;
    const int tok1 = (w1 < L) ? toks[w1] : 0;
    const float* p0 = emb + ((size_t)tok0 << 9) + lg * 8;
    const float* p1 = emb + ((size_t)tok1 << 9) + lg * 8;

    f32x4 acc[2][4];
    #pragma unroll
    for (int mt = 0; mt < 2; ++mt)
        #pragma unroll
        for (int nt = 0; nt < 4; ++nt)
            acc[mt][nt] = (f32x4){0.f, 0.f, 0.f, 0.f};

    // ---- pre = bag @ W_pre via MFMA: K=512 in 16 steps of 32 ----
    #pragma unroll 4
    for (int ks = 0; ks < 16; ++ks) {
        const float4* a0p = (const float4*)(p0 + ks * 32);
        const float4* a1p = (const float4*)(p1 + ks * 32);
        float4 x0 = a0p[0], y0 = a0p[1];
        float4 x1 = a1p[0], y1 = a1p[1];
        bf16x8 a0 = make_frag(x0, y0);
        bf16x8 a1 = make_frag(x1, y1);
        bf16x8 b0 = wb[(ks * 4 + 0) * 64 + lane];
        bf16x8 b1 = wb[(ks * 4 + 1) * 64 + lane];
        bf16x8 b2 = wb[(ks * 4 + 2) * 64 + lane];
        bf16x8 b3 = wb[(ks * 4 + 3) * 64 + lane];
        acc[0][0] = __builtin_amdgcn_mfma_f32_16x16x32_bf16(a0, b0, acc[0][0], 0, 0, 0);
        acc[0][1] = __builtin_amdgcn_mfma_f32_16x16x32_bf16(a0, b1, acc[0][1], 0, 0, 0);
        acc[0][2] = __builtin_amdgcn_mfma_f32_16x16x32_bf16(a0, b2, acc[0][2], 0, 0, 0);
        acc[0][3] = __builtin_amdgcn_mfma_f32_16x16x32_bf16(a0, b3, acc[0][3], 0, 0, 0);
        acc[1][0] = __builtin_amdgcn_mfma_f32_16x16x32_bf16(a1, b0, acc[1][0], 0, 0, 0);
        acc[1][1] = __builtin_amdgcn_mfma_f32_16x16x32_bf16(a1, b1, acc[1][1], 0, 0, 0);
        acc[1][2] = __builtin_amdgcn_mfma_f32_16x16x32_bf16(a1, b2, acc[1][2], 0, 0, 0);
        acc[1][3] = __builtin_amdgcn_mfma_f32_16x16x32_bf16(a1, b3, acc[1][3], 0, 0, 0);
    }

    // ---- energy: e[w] = sum_k tanh(pre + b_pre + q) * v ----
    // lane covers cols  nt*16 + lr ; rows  mt*16 + lg*4 + r
    float qb[4], vv[4];
    #pragma unroll
    for (int nt = 0; nt < 4; ++nt) {
        int cidx = nt * 16 + lr;
        qb[nt] = q[b * DKK + cidx] + b_pre[cidx];
        vv[nt] = v[cidx];
    }
    #pragma unroll
    for (int mt = 0; mt < 2; ++mt) {
        #pragma unroll
        for (int r = 0; r < 4; ++r) {
            float s = 0.0f;
            #pragma unroll
            for (int nt = 0; nt < 4; ++nt) {
                float pre = acc[mt][nt][r] + qb[nt];
                float ez = __expf(2.0f * pre);                 // tanh(x) = 1 - 2/(e^2x+1)
                float th = 1.0f - 2.0f * __builtin_amdgcn_rcpf(ez + 1.0f);
                s += th * vv[nt];
            }
            s += __shfl_xor(s, 1);
            s += __shfl_xor(s, 2);
            s += __shfl_xor(s, 4);
            s += __shfl_xor(s, 8);
            if (lr == 0) sh_e[wid][mt * 16 + lg * 4 + r] = s;
        }
    }
    __syncthreads();

    // ---- softmax over all 32 word slots (reference has no length mask here) ----
    {
        float e2 = sh_e[wid][lane & 31];
        float mx = e2;
        #pragma unroll
        for (int s = 1; s < 32; s <<= 1) mx = fmaxf(mx, __shfl_xor(mx, s));
        float ex = __expf(e2 - mx);
        float sm = ex;
        #pragma unroll
        for (int s = 1; s < 32; s <<= 1) sm += __shfl_xor(sm, s);
        if (lane < 32) sh_s[wid][lane] = ex / sm;
    }
    __syncthreads();

    // ---- context: lane owns 8 consecutive d's; re-read bag rows (L2-hot) ----
    const int d0 = lane * 8;
    float c00 = 0, c01 = 0, c02 = 0, c03 = 0, c04 = 0, c05 = 0, c06 = 0, c07 = 0;
    #pragma unroll 8
    for (int w = 0; w < WW; ++w) {
        float s = sh_s[wid][w];
        const float4* pr = (const float4*)(emb + ((size_t)sh_tok[wid][w] << 9) + d0);
        float4 x0 = pr[0], x1 = pr[1];
        c00 += s * x0.x; c01 += s * x0.y; c02 += s * x0.z; c03 += s * x0.w;
        c04 += s * x1.x; c05 += s * x1.y; c06 += s * x1.z; c07 += s * x1.w;
    }
    const bool outmask = (n < node_sizes[b * CCC + c]) && (c < cross_lengths[b]);
    if (!outmask) { c00 = c01 = c02 = c03 = c04 = c05 = c06 = c07 = 0.f; }
    float4* op = (float4*)(out + (size_t)t * DD + d0);
    op[0] = float4{c00, c01, c02, c03};
    op[1] = float4{c04, c05, c06, c07};
}

extern "C" void kernel_launch(void* const* d_in, const int* in_sizes, int n_in,
                              void* d_out, int out_size, void* d_ws, size_t ws_size,
                              hipStream_t stream) {
    const int*   token_ids     = (const int*)d_in[0];
    const int*   node_lengths  = (const int*)d_in[1];
    const int*   node_sizes    = (const int*)d_in[2];
    const int*   cross_lengths = (const int*)d_in[3];
    const float* con_hidden    = (const float*)d_in[4];
    const float* emb           = (const float*)d_in[5];
    const float* W_pre         = (const float*)d_in[6];
    const float* b_pre         = (const float*)d_in[7];
    const float* W_q           = (const float*)d_in[8];
    const float* v             = (const float*)d_in[9];

    float*  out     = (float*)d_out;
    float*  hid_out = out + (size_t)TB * DD;              // second output
    float*  q       = (float*)d_ws;                       // 16 KB
    bf16x8* wb      = (bf16x8*)((char*)d_ws + 64 * 64 * 4); // 64 KB packed W_pre

    prep_kernel<<<64, 64, 0, stream>>>(con_hidden, W_q, q, hid_out);
    pack_wpre<<<64, 64, 0, stream>>>(W_pre, wb);
    bag_kernel<<<TB / 4, 256, 0, stream>>>(token_ids, node_lengths, node_sizes,
                                           cross_lengths, emb, b_pre, v, q, wb, out);
}

// Round 4
// 98.802 us; speedup vs baseline: 10.0680x; 1.2801x over previous
//
#include <hip/hip_runtime.h>
#include <hip/hip_bf16.h>

#define TB   8192   // B*C*N bags
#define WW   32     // words per bag
#define DD   512    // d_model
#define DKK  64     // attention dim
#define CCC  4      // max cross

using bf16x8 = __attribute__((ext_vector_type(8))) short;
using f32x4  = __attribute__((ext_vector_type(4))) float;

__device__ __forceinline__ unsigned short f2bf(float x) {
    union { float f; unsigned u; } u;
    u.f = x;
    unsigned r = u.u + 0x7fffu + ((u.u >> 16) & 1u);
    return (unsigned short)(r >> 16);
}

// pack two float4 (8 consecutive fp32) into one bf16x8 fragment (RNE)
__device__ __forceinline__ bf16x8 make_frag(float4 x, float4 y) {
    union { bf16x8 v; unsigned short s[8]; } u;
    u.s[0] = f2bf(x.x); u.s[1] = f2bf(x.y); u.s[2] = f2bf(x.z); u.s[3] = f2bf(x.w);
    u.s[4] = f2bf(y.x); u.s[5] = f2bf(y.y); u.s[6] = f2bf(y.z); u.s[7] = f2bf(y.w);
    return u.v;
}

// fma 8 bf16 elems (packed) into fp32 accumulators: cx[j] += s * elem[j]
__device__ __forceinline__ void bfx8_fma(float* cx, bf16x8 r, float s) {
    union { bf16x8 v; unsigned u[4]; } u; u.v = r;
    #pragma unroll
    for (int j = 0; j < 4; ++j) {
        float lo = __uint_as_float(u.u[j] << 16);
        float hi = __uint_as_float(u.u[j] & 0xffff0000u);
        cx[2 * j]     += s * lo;
        cx[2 * j + 1] += s * hi;
    }
}

// Kernel A: q[b,k] = dot(con_hidden[b,:], W_q[:,k]); copy hidden to output 2.
__global__ __launch_bounds__(64) void prep_kernel(
    const float* __restrict__ con_hidden,  // [64][512]
    const float* __restrict__ W_q,         // [512][64]
    float* __restrict__ qout,              // [64][64]
    float* __restrict__ hid_out)           // [64][512]
{
    const int b = blockIdx.x;
    const int k = threadIdx.x;  // 0..63
    const float* h = con_hidden + b * DD;
    float acc = 0.0f;
    #pragma unroll 8
    for (int d = 0; d < DD; ++d) acc += h[d] * W_q[d * DKK + k];
    qout[b * DKK + k] = acc;
    const float4* src = (const float4*)h;
    float4* dst = (float4*)(hid_out + b * DD);
    for (int i = k; i < DD / 4; i += 64) dst[i] = src[i];
}

// Kernel B: pack W_pre (512x64 fp32) into B-fragment-major bf16.
// frag (ks, nt): lane l holds W_pre[ks*32 + (l>>4)*8 + j][nt*16 + (l&15)], j=0..7
__global__ __launch_bounds__(64) void pack_wpre(
    const float* __restrict__ W_pre,
    bf16x8* __restrict__ wb)               // 64 frags * 64 lanes * 16B = 64 KB
{
    const int blk = blockIdx.x;            // ks*4 + nt  (64 blocks)
    const int ks = blk >> 2, nt = blk & 3;
    const int l  = threadIdx.x;
    const int lr = l & 15, lg = l >> 4;
    union { bf16x8 v; unsigned short s[8]; } u;
    #pragma unroll
    for (int j = 0; j < 8; ++j) {
        int k = ks * 32 + lg * 8 + j;
        u.s[j] = f2bf(W_pre[k * DKK + nt * 16 + lr]);
    }
    wb[blk * 64 + l] = u.v;
}

// Kernel C: emb fp32 -> bf16 (RNE), 8 elems per thread.
__global__ __launch_bounds__(256) void conv_emb(
    const float* __restrict__ e,
    unsigned short* __restrict__ o)
{
    const size_t i = ((size_t)blockIdx.x * 256 + threadIdx.x) * 8;
    const float4* p = (const float4*)(e + i);
    float4 a = p[0], b = p[1];
    *(bf16x8*)(o + i) = make_frag(a, b);
}

// Kernel D: one WAVE per bag. pipelined MFMA pre-GEMM -> energy -> softmax -> context.
template<bool BF16E>
__global__ __launch_bounds__(256) void bag_kernel(
    const int* __restrict__ token_ids,     // [8192][32]
    const int* __restrict__ node_lengths,  // [8192]
    const int* __restrict__ node_sizes,    // [256]
    const int* __restrict__ cross_lengths, // [64]
    const float* __restrict__ embf,        // [32000][512] fp32, row 0 zeros
    const unsigned short* __restrict__ embh, // [32000][512] bf16 (if BF16E)
    const float* __restrict__ b_pre,       // [64]
    const float* __restrict__ v,           // [64]
    const float* __restrict__ q,           // [64][64]
    const bf16x8* __restrict__ wb,         // packed W_pre fragments
    float* __restrict__ out)               // [8192][512]
{
    const int wid  = threadIdx.x >> 6;
    const int lane = threadIdx.x & 63;
    const int t = blockIdx.x * 4 + wid;
    const int b = t >> 7, cn = t & 127, c = cn >> 5, n = cn & 31;
    const int lr = lane & 15, lg = lane >> 4;

    __shared__ int   sh_tok[4][32];
    __shared__ float sh_e[4][32];
    __shared__ float sh_s[4][32];

    const int L = node_lengths[t];
    const int* toks = token_ids + t * WW;

    if (lane < 32) {
        int tok = toks[lane];
        sh_tok[wid][lane] = (lane < L) ? tok : 0;   // emb row 0 is all-zero
    }

    // per-lane A-row pointers for the two M-tiles (words lr and 16+lr)
    const int w1 = 16 + lr;
    const int tok0 = (lr < L) ? toks[lr] : 0;
    const int tok1 = (w1 < L) ? toks[w1] : 0;

    const unsigned short* hp0 = nullptr; const unsigned short* hp1 = nullptr;
    const float* fp0 = nullptr; const float* fp1 = nullptr;
    if constexpr (BF16E) {
        hp0 = embh + ((size_t)tok0 << 9) + lg * 8;
        hp1 = embh + ((size_t)tok1 << 9) + lg * 8;
    } else {
        fp0 = embf + ((size_t)tok0 << 9) + lg * 8;
        fp1 = embf + ((size_t)tok1 << 9) + lg * 8;
    }

    f32x4 acc[2][4];
    #pragma unroll
    for (int mt = 0; mt < 2; ++mt)
        #pragma unroll
        for (int nt = 0; nt < 4; ++nt)
            acc[mt][nt] = (f32x4){0.f, 0.f, 0.f, 0.f};

    // ---- pre = bag @ W_pre via MFMA, explicit 3-slot software pipeline ----
    bf16x8 A0[3], A1[3], B0[3], B1[3], B2[3], B3[3];
    float4 F0x[3], F0y[3], F1x[3], F1y[3];

    auto issue = [&](int ks, int sl) {
        B0[sl] = wb[(ks * 4 + 0) * 64 + lane];
        B1[sl] = wb[(ks * 4 + 1) * 64 + lane];
        B2[sl] = wb[(ks * 4 + 2) * 64 + lane];
        B3[sl] = wb[(ks * 4 + 3) * 64 + lane];
        if constexpr (BF16E) {
            A0[sl] = *(const bf16x8*)(hp0 + ks * 32);
            A1[sl] = *(const bf16x8*)(hp1 + ks * 32);
        } else {
            const float4* a0p = (const float4*)(fp0 + ks * 32);
            const float4* a1p = (const float4*)(fp1 + ks * 32);
            F0x[sl] = a0p[0]; F0y[sl] = a0p[1];
            F1x[sl] = a1p[0]; F1y[sl] = a1p[1];
        }
    };
    auto compute = [&](int ks, int sl) {
        bf16x8 a0, a1;
        if constexpr (BF16E) { a0 = A0[sl]; a1 = A1[sl]; }
        else { a0 = make_frag(F0x[sl], F0y[sl]); a1 = make_frag(F1x[sl], F1y[sl]); }
        acc[0][0] = __builtin_amdgcn_mfma_f32_16x16x32_bf16(a0, B0[sl], acc[0][0], 0, 0, 0);
        acc[0][1] = __builtin_amdgcn_mfma_f32_16x16x32_bf16(a0, B1[sl], acc[0][1], 0, 0, 0);
        acc[0][2] = __builtin_amdgcn_mfma_f32_16x16x32_bf16(a0, B2[sl], acc[0][2], 0, 0, 0);
        acc[0][3] = __builtin_amdgcn_mfma_f32_16x16x32_bf16(a0, B3[sl], acc[0][3], 0, 0, 0);
        acc[1][0] = __builtin_amdgcn_mfma_f32_16x16x32_bf16(a1, B0[sl], acc[1][0], 0, 0, 0);
        acc[1][1] = __builtin_amdgcn_mfma_f32_16x16x32_bf16(a1, B1[sl], acc[1][1], 0, 0, 0);
        acc[1][2] = __builtin_amdgcn_mfma_f32_16x16x32_bf16(a1, B2[sl], acc[1][2], 0, 0, 0);
        acc[1][3] = __builtin_amdgcn_mfma_f32_16x16x32_bf16(a1, B3[sl], acc[1][3], 0, 0, 0);
    };

    issue(0, 0);
    issue(1, 1);
    #pragma unroll
    for (int ks = 0; ks < 16; ++ks) {
        if (ks + 2 < 16) issue(ks + 2, (ks + 2) % 3);
        compute(ks, ks % 3);
    }

    // ---- energy: e[w] = sum_k tanh(pre + b_pre + q) * v ----
    float qb[4], vv[4];
    #pragma unroll
    for (int nt = 0; nt < 4; ++nt) {
        int cidx = nt * 16 + lr;
        qb[nt] = q[b * DKK + cidx] + b_pre[cidx];
        vv[nt] = v[cidx];
    }
    #pragma unroll
    for (int mt = 0; mt < 2; ++mt) {
        #pragma unroll
        for (int r = 0; r < 4; ++r) {
            float s = 0.0f;
            #pragma unroll
            for (int nt = 0; nt < 4; ++nt) {
                float pre = acc[mt][nt][r] + qb[nt];
                float ez = __expf(2.0f * pre);                 // tanh(x) = 1 - 2/(e^2x+1)
                float th = 1.0f - 2.0f * __builtin_amdgcn_rcpf(ez + 1.0f);
                s += th * vv[nt];
            }
            s += __shfl_xor(s, 1);
            s += __shfl_xor(s, 2);
            s += __shfl_xor(s, 4);
            s += __shfl_xor(s, 8);
            if (lr == 0) sh_e[wid][mt * 16 + lg * 4 + r] = s;
        }
    }
    __syncthreads();

    // ---- softmax over all 32 word slots (reference has no length mask here) ----
    {
        float e2 = sh_e[wid][lane & 31];
        float mx = e2;
        #pragma unroll
        for (int s = 1; s < 32; s <<= 1) mx = fmaxf(mx, __shfl_xor(mx, s));
        float ex = __expf(e2 - mx);
        float sm = ex;
        #pragma unroll
        for (int s = 1; s < 32; s <<= 1) sm += __shfl_xor(sm, s);
        if (lane < 32) sh_s[wid][lane] = ex / sm;
    }
    __syncthreads();

    // ---- context: lane owns 8 consecutive d's; pipelined re-read (L2-hot) ----
    const int d0 = lane * 8;
    float cx[8];
    #pragma unroll
    for (int j = 0; j < 8; ++j) cx[j] = 0.0f;

    if constexpr (BF16E) {
        bf16x8 R[4];
        auto cissue = [&](int w, int sl) {
            R[sl] = *(const bf16x8*)(embh + ((size_t)sh_tok[wid][w] << 9) + d0);
        };
        cissue(0, 0); cissue(1, 1); cissue(2, 2); cissue(3, 3);
        #pragma unroll
        for (int w = 0; w < WW; ++w) {
            bf16x8 r = R[w % 4];
            if (w + 4 < WW) cissue(w + 4, (w + 4) % 4);
            bfx8_fma(cx, r, sh_s[wid][w]);
        }
    } else {
        float4 Rx[4], Ry[4];
        auto cissue = [&](int w, int sl) {
            const float4* pr = (const float4*)(embf + ((size_t)sh_tok[wid][w] << 9) + d0);
            Rx[sl] = pr[0]; Ry[sl] = pr[1];
        };
        cissue(0, 0); cissue(1, 1); cissue(2, 2); cissue(3, 3);
        #pragma unroll
        for (int w = 0; w < WW; ++w) {
            float4 x0 = Rx[w % 4], x1 = Ry[w % 4];
            if (w + 4 < WW) cissue(w + 4, (w + 4) % 4);
            float s = sh_s[wid][w];
            cx[0] += s * x0.x; cx[1] += s * x0.y; cx[2] += s * x0.z; cx[3] += s * x0.w;
            cx[4] += s * x1.x; cx[5] += s * x1.y; cx[6] += s * x1.z; cx[7] += s * x1.w;
        }
    }

    const bool outmask = (n < node_sizes[b * CCC + c]) && (c < cross_lengths[b]);
    if (!outmask) {
        #pragma unroll
        for (int j = 0; j < 8; ++j) cx[j] = 0.0f;
    }
    float4* op = (float4*)(out + (size_t)t * DD + d0);
    op[0] = float4{cx[0], cx[1], cx[2], cx[3]};
    op[1] = float4{cx[4], cx[5], cx[6], cx[7]};
}

extern "C" void kernel_launch(void* const* d_in, const int* in_sizes, int n_in,
                              void* d_out, int out_size, void* d_ws, size_t ws_size,
                              hipStream_t stream) {
    const int*   token_ids     = (const int*)d_in[0];
    const int*   node_lengths  = (const int*)d_in[1];
    const int*   node_sizes    = (const int*)d_in[2];
    const int*   cross_lengths = (const int*)d_in[3];
    const float* con_hidden    = (const float*)d_in[4];
    const float* emb           = (const float*)d_in[5];
    const float* W_pre         = (const float*)d_in[6];
    const float* b_pre         = (const float*)d_in[7];
    const float* W_q           = (const float*)d_in[8];
    const float* v             = (const float*)d_in[9];

    float*  out     = (float*)d_out;
    float*  hid_out = out + (size_t)TB * DD;                 // second output
    float*  q       = (float*)d_ws;                          // 16 KB
    bf16x8* wb      = (bf16x8*)((char*)d_ws + 16 * 1024);    // 64 KB packed W_pre
    unsigned short* embh = (unsigned short*)((char*)d_ws + 80 * 1024);  // 32 MB

    const size_t need = 80 * 1024 + (size_t)32000 * DD * 2;

    prep_kernel<<<64, 64, 0, stream>>>(con_hidden, W_q, q, hid_out);
    pack_wpre<<<64, 64, 0, stream>>>(W_pre, wb);

    if (ws_size >= need) {
        conv_emb<<<(32000 * DD / 8) / 256, 256, 0, stream>>>(emb, embh);
        bag_kernel<true><<<TB / 4, 256, 0, stream>>>(
            token_ids, node_lengths, node_sizes, cross_lengths,
            emb, embh, b_pre, v, q, wb, out);
    } else {
        bag_kernel<false><<<TB / 4, 256, 0, stream>>>(
            token_ids, node_lengths, node_sizes, cross_lengths,
            emb, nullptr, b_pre, v, q, wb, out);
    }
}

// Round 5
// 92.403 us; speedup vs baseline: 10.7651x; 1.0692x over previous
//
#include <hip/hip_runtime.h>
#include <hip/hip_bf16.h>

#define TB   8192   // B*C*N bags
#define WW   32     // words per bag
#define DD   512    // d_model
#define DKK  64     // attention dim
#define CCC  4      // max cross

#define CONV_BLKS 8000   // 32000*512/8/256

using bf16x8 = __attribute__((ext_vector_type(8))) short;
using f32x4  = __attribute__((ext_vector_type(4))) float;

__device__ __forceinline__ unsigned short f2bf(float x) {
    union { float f; unsigned u; } u;
    u.f = x;
    unsigned r = u.u + 0x7fffu + ((u.u >> 16) & 1u);
    return (unsigned short)(r >> 16);
}

// pack two float4 (8 consecutive fp32) into one bf16x8 fragment (RNE)
__device__ __forceinline__ bf16x8 make_frag(float4 x, float4 y) {
    union { bf16x8 v; unsigned short s[8]; } u;
    u.s[0] = f2bf(x.x); u.s[1] = f2bf(x.y); u.s[2] = f2bf(x.z); u.s[3] = f2bf(x.w);
    u.s[4] = f2bf(y.x); u.s[5] = f2bf(y.y); u.s[6] = f2bf(y.z); u.s[7] = f2bf(y.w);
    return u.v;
}

// fma 8 bf16 elems (packed) into fp32 accumulators: cx[j] += s * elem[j]
__device__ __forceinline__ void bfx8_fma(float* cx, bf16x8 r, float s) {
    union { bf16x8 v; unsigned u[4]; } u; u.v = r;
    #pragma unroll
    for (int j = 0; j < 4; ++j) {
        float lo = __uint_as_float(u.u[j] << 16);
        float hi = __uint_as_float(u.u[j] & 0xffff0000u);
        cx[2 * j]     += s * lo;
        cx[2 * j + 1] += s * hi;
    }
}

// ---------------- fused preprocessing ----------------
// blocks [0, CONV_BLKS)            : emb fp32 -> bf16
// blocks [CONV_BLKS, +64)          : prep (q GEMM + hidden copy), 64 active thr
// blocks [CONV_BLKS+64, +128)      : pack W_pre fragments, 64 active thr
__global__ __launch_bounds__(256) void preproc_kernel(
    const float* __restrict__ emb,
    unsigned short* __restrict__ embh,
    const float* __restrict__ con_hidden,  // [64][512]
    const float* __restrict__ W_q,         // [512][64]
    float* __restrict__ qout,              // [64][64]
    float* __restrict__ hid_out,           // [64][512]
    const float* __restrict__ W_pre,       // [512][64]
    bf16x8* __restrict__ wb)               // 64 frags * 64 lanes
{
    const int blk = blockIdx.x;
    const int tid = threadIdx.x;
    if (blk < CONV_BLKS) {
        const size_t i = ((size_t)blk * 256 + tid) * 8;
        const float4* p = (const float4*)(emb + i);
        float4 a = p[0], b = p[1];
        *(bf16x8*)(embh + i) = make_frag(a, b);
    } else if (blk < CONV_BLKS + 64) {
        if (tid >= 64) return;
        const int b = blk - CONV_BLKS;
        const int k = tid;
        const float* h = con_hidden + b * DD;
        float acc = 0.0f;
        #pragma unroll 8
        for (int d = 0; d < DD; ++d) acc += h[d] * W_q[d * DKK + k];
        qout[b * DKK + k] = acc;
        const float4* src = (const float4*)h;
        float4* dst = (float4*)(hid_out + b * DD);
        for (int i = k; i < DD / 4; i += 64) dst[i] = src[i];
    } else {
        if (tid >= 64) return;
        const int fb = blk - CONV_BLKS - 64;   // ks*4 + nt
        const int ks = fb >> 2, nt = fb & 3;
        const int lr = tid & 15, lg = tid >> 4;
        union { bf16x8 v; unsigned short s[8]; } u;
        #pragma unroll
        for (int j = 0; j < 8; ++j) {
            int k = ks * 32 + lg * 8 + j;
            u.s[j] = f2bf(W_pre[k * DKK + nt * 16 + lr]);
        }
        wb[fb * 64 + tid] = u.v;
    }
}

// fallback preprocessing (fp32 path), same as before
__global__ __launch_bounds__(64) void prep_kernel(
    const float* __restrict__ con_hidden, const float* __restrict__ W_q,
    float* __restrict__ qout, float* __restrict__ hid_out)
{
    const int b = blockIdx.x;
    const int k = threadIdx.x;
    const float* h = con_hidden + b * DD;
    float acc = 0.0f;
    #pragma unroll 8
    for (int d = 0; d < DD; ++d) acc += h[d] * W_q[d * DKK + k];
    qout[b * DKK + k] = acc;
    const float4* src = (const float4*)h;
    float4* dst = (float4*)(hid_out + b * DD);
    for (int i = k; i < DD / 4; i += 64) dst[i] = src[i];
}

__global__ __launch_bounds__(64) void pack_wpre(
    const float* __restrict__ W_pre, bf16x8* __restrict__ wb)
{
    const int blk = blockIdx.x;
    const int ks = blk >> 2, nt = blk & 3;
    const int l  = threadIdx.x;
    const int lr = l & 15, lg = l >> 4;
    union { bf16x8 v; unsigned short s[8]; } u;
    #pragma unroll
    for (int j = 0; j < 8; ++j) {
        int k = ks * 32 + lg * 8 + j;
        u.s[j] = f2bf(W_pre[k * DKK + nt * 16 + lr]);
    }
    wb[blk * 64 + l] = u.v;
}

// ---------------- main bag kernel ----------------
template<bool BF16E>
__global__ __launch_bounds__(256) void bag_kernel(
    const int* __restrict__ token_ids,     // [8192][32]
    const int* __restrict__ node_lengths,  // [8192]
    const int* __restrict__ node_sizes,    // [256]
    const int* __restrict__ cross_lengths, // [64]
    const float* __restrict__ embf,        // [32000][512] fp32, row 0 zeros
    const unsigned short* __restrict__ embh, // [32000][512] bf16 (if BF16E)
    const float* __restrict__ b_pre,       // [64]
    const float* __restrict__ v,           // [64]
    const float* __restrict__ q,           // [64][64]
    const bf16x8* __restrict__ wb,         // packed W_pre fragments
    float* __restrict__ out)               // [8192][512]
{
    const int wid  = threadIdx.x >> 6;
    const int lane = threadIdx.x & 63;
    const int t = blockIdx.x * 4 + wid;
    const int b = t >> 7, cn = t & 127, c = cn >> 5, n = cn & 31;
    const int lr = lane & 15, lg = lane >> 4;

    __shared__ int   sh_tok[4][32];
    __shared__ float sh_e[4][32];
    __shared__ float sh_s[4][32];

    const int L = node_lengths[t];
    const int* toks = token_ids + t * WW;

    if (lane < 32) {
        int tok = toks[lane];
        sh_tok[wid][lane] = (lane < L) ? tok : 0;   // emb row 0 is all-zero
    }

    // per-lane A-row pointers for the two M-tiles (words lr and 16+lr)
    const int w1 = 16 + lr;
    const int tok0 = (lr < L) ? toks[lr] : 0;
    const int tok1 = (w1 < L) ? toks[w1] : 0;

    const unsigned short* hp0 = nullptr; const unsigned short* hp1 = nullptr;
    const float* fp0 = nullptr; const float* fp1 = nullptr;
    if constexpr (BF16E) {
        hp0 = embh + ((size_t)tok0 << 9) + lg * 8;
        hp1 = embh + ((size_t)tok1 << 9) + lg * 8;
    } else {
        fp0 = embf + ((size_t)tok0 << 9) + lg * 8;
        fp1 = embf + ((size_t)tok1 << 9) + lg * 8;
    }

    f32x4 acc[2][4];
    #pragma unroll
    for (int mt = 0; mt < 2; ++mt)
        #pragma unroll
        for (int nt = 0; nt < 4; ++nt)
            acc[mt][nt] = (f32x4){0.f, 0.f, 0.f, 0.f};

    if constexpr (BF16E) {
        // ---- MFMA pre-GEMM: A gather prefetched 4 deep, B 2 deep, pinned ----
        bf16x8 A0[4], A1[4];
        bf16x8 Bs[2][4];

        auto loadA = [&](int ks, int sl) {
            A0[sl] = *(const bf16x8*)(hp0 + ks * 32);
            A1[sl] = *(const bf16x8*)(hp1 + ks * 32);
        };
        auto loadB = [&](int ks, int sl) {
            #pragma unroll
            for (int nt = 0; nt < 4; ++nt)
                Bs[sl][nt] = wb[(ks * 4 + nt) * 64 + lane];
        };

        loadA(0, 0); loadA(1, 1); loadA(2, 2); loadA(3, 3);
        loadB(0, 0);
        asm volatile("" ::: "memory");   // pin prologue loads

        #pragma unroll
        for (int ks = 0; ks < 16; ++ks) {
            // consume current A slot BEFORE overwriting it (slot (ks+4)&3 == ks&3)
            bf16x8 a0 = A0[ks & 3], a1 = A1[ks & 3];
            if (ks + 4 < 16) loadA(ks + 4, (ks + 4) & 3);
            if (ks + 1 < 16) loadB(ks + 1, (ks + 1) & 1);
            asm volatile("" ::: "memory");  // loads cannot sink past this point
            const int bs = ks & 1;
            acc[0][0] = __builtin_amdgcn_mfma_f32_16x16x32_bf16(a0, Bs[bs][0], acc[0][0], 0, 0, 0);
            acc[0][1] = __builtin_amdgcn_mfma_f32_16x16x32_bf16(a0, Bs[bs][1], acc[0][1], 0, 0, 0);
            acc[0][2] = __builtin_amdgcn_mfma_f32_16x16x32_bf16(a0, Bs[bs][2], acc[0][2], 0, 0, 0);
            acc[0][3] = __builtin_amdgcn_mfma_f32_16x16x32_bf16(a0, Bs[bs][3], acc[0][3], 0, 0, 0);
            acc[1][0] = __builtin_amdgcn_mfma_f32_16x16x32_bf16(a1, Bs[bs][0], acc[1][0], 0, 0, 0);
            acc[1][1] = __builtin_amdgcn_mfma_f32_16x16x32_bf16(a1, Bs[bs][1], acc[1][1], 0, 0, 0);
            acc[1][2] = __builtin_amdgcn_mfma_f32_16x16x32_bf16(a1, Bs[bs][2], acc[1][2], 0, 0, 0);
            acc[1][3] = __builtin_amdgcn_mfma_f32_16x16x32_bf16(a1, Bs[bs][3], acc[1][3], 0, 0, 0);
        }
    } else {
        // fp32 fallback, simple 3-slot rotation (no pinning)
        bf16x8 B0[3], B1[3], B2[3], B3[3];
        float4 F0x[3], F0y[3], F1x[3], F1y[3];
        auto issue = [&](int ks, int sl) {
            B0[sl] = wb[(ks * 4 + 0) * 64 + lane];
            B1[sl] = wb[(ks * 4 + 1) * 64 + lane];
            B2[sl] = wb[(ks * 4 + 2) * 64 + lane];
            B3[sl] = wb[(ks * 4 + 3) * 64 + lane];
            const float4* a0p = (const float4*)(fp0 + ks * 32);
            const float4* a1p = (const float4*)(fp1 + ks * 32);
            F0x[sl] = a0p[0]; F0y[sl] = a0p[1];
            F1x[sl] = a1p[0]; F1y[sl] = a1p[1];
        };
        auto compute = [&](int ks, int sl) {
            bf16x8 a0 = make_frag(F0x[sl], F0y[sl]);
            bf16x8 a1 = make_frag(F1x[sl], F1y[sl]);
            acc[0][0] = __builtin_amdgcn_mfma_f32_16x16x32_bf16(a0, B0[sl], acc[0][0], 0, 0, 0);
            acc[0][1] = __builtin_amdgcn_mfma_f32_16x16x32_bf16(a0, B1[sl], acc[0][1], 0, 0, 0);
            acc[0][2] = __builtin_amdgcn_mfma_f32_16x16x32_bf16(a0, B2[sl], acc[0][2], 0, 0, 0);
            acc[0][3] = __builtin_amdgcn_mfma_f32_16x16x32_bf16(a0, B3[sl], acc[0][3], 0, 0, 0);
            acc[1][0] = __builtin_amdgcn_mfma_f32_16x16x32_bf16(a1, B0[sl], acc[1][0], 0, 0, 0);
            acc[1][1] = __builtin_amdgcn_mfma_f32_16x16x32_bf16(a1, B1[sl], acc[1][1], 0, 0, 0);
            acc[1][2] = __builtin_amdgcn_mfma_f32_16x16x32_bf16(a1, B2[sl], acc[1][2], 0, 0, 0);
            acc[1][3] = __builtin_amdgcn_mfma_f32_16x16x32_bf16(a1, B3[sl], acc[1][3], 0, 0, 0);
        };
        issue(0, 0); issue(1, 1);
        #pragma unroll
        for (int ks = 0; ks < 16; ++ks) {
            if (ks + 2 < 16) issue(ks + 2, (ks + 2) % 3);
            compute(ks, ks % 3);
        }
    }

    // ---- energy: e[w] = sum_k tanh(pre + b_pre + q) * v ----
    float qb[4], vv[4];
    #pragma unroll
    for (int nt = 0; nt < 4; ++nt) {
        int cidx = nt * 16 + lr;
        qb[nt] = q[b * DKK + cidx] + b_pre[cidx];
        vv[nt] = v[cidx];
    }
    #pragma unroll
    for (int mt = 0; mt < 2; ++mt) {
        #pragma unroll
        for (int r = 0; r < 4; ++r) {
            float s = 0.0f;
            #pragma unroll
            for (int nt = 0; nt < 4; ++nt) {
                float pre = acc[mt][nt][r] + qb[nt];
                float ez = __expf(2.0f * pre);                 // tanh(x) = 1 - 2/(e^2x+1)
                float th = 1.0f - 2.0f * __builtin_amdgcn_rcpf(ez + 1.0f);
                s += th * vv[nt];
            }
            s += __shfl_xor(s, 1);
            s += __shfl_xor(s, 2);
            s += __shfl_xor(s, 4);
            s += __shfl_xor(s, 8);
            if (lr == 0) sh_e[wid][mt * 16 + lg * 4 + r] = s;
        }
    }
    __syncthreads();

    // ---- softmax over all 32 word slots (reference has no length mask here) ----
    {
        float e2 = sh_e[wid][lane & 31];
        float mx = e2;
        #pragma unroll
        for (int s = 1; s < 32; s <<= 1) mx = fmaxf(mx, __shfl_xor(mx, s));
        float ex = __expf(e2 - mx);
        float sm = ex;
        #pragma unroll
        for (int s = 1; s < 32; s <<= 1) sm += __shfl_xor(sm, s);
        if (lane < 32) sh_s[wid][lane] = ex / sm;
    }
    __syncthreads();

    // ---- context: lane owns 8 consecutive d's; pipelined re-read (L1/L2-hot) ----
    const int d0 = lane * 8;
    float cx[8];
    #pragma unroll
    for (int j = 0; j < 8; ++j) cx[j] = 0.0f;

    if constexpr (BF16E) {
        bf16x8 R[4];
        auto cissue = [&](int w, int sl) {
            R[sl] = *(const bf16x8*)(embh + ((size_t)sh_tok[wid][w] << 9) + d0);
        };
        cissue(0, 0); cissue(1, 1); cissue(2, 2); cissue(3, 3);
        asm volatile("" ::: "memory");
        #pragma unroll
        for (int w = 0; w < WW; ++w) {
            bf16x8 r = R[w & 3];                // consume before slot reuse
            float s = sh_s[wid][w];
            if (w + 4 < WW) cissue(w + 4, (w + 4) & 3);
            asm volatile("" ::: "memory");
            bfx8_fma(cx, r, s);
        }
    } else {
        float4 Rx[4], Ry[4];
        auto cissue = [&](int w, int sl) {
            const float4* pr = (const float4*)(embf + ((size_t)sh_tok[wid][w] << 9) + d0);
            Rx[sl] = pr[0]; Ry[sl] = pr[1];
        };
        cissue(0, 0); cissue(1, 1); cissue(2, 2); cissue(3, 3);
        #pragma unroll
        for (int w = 0; w < WW; ++w) {
            float4 x0 = Rx[w & 3], x1 = Ry[w & 3];
            float s = sh_s[wid][w];
            if (w + 4 < WW) cissue(w + 4, (w + 4) & 3);
            cx[0] += s * x0.x; cx[1] += s * x0.y; cx[2] += s * x0.z; cx[3] += s * x0.w;
            cx[4] += s * x1.x; cx[5] += s * x1.y; cx[6] += s * x1.z; cx[7] += s * x1.w;
        }
    }

    const bool outmask = (n < node_sizes[b * CCC + c]) && (c < cross_lengths[b]);
    if (!outmask) {
        #pragma unroll
        for (int j = 0; j < 8; ++j) cx[j] = 0.0f;
    }
    float4* op = (float4*)(out + (size_t)t * DD + d0);
    op[0] = float4{cx[0], cx[1], cx[2], cx[3]};
    op[1] = float4{cx[4], cx[5], cx[6], cx[7]};
}

extern "C" void kernel_launch(void* const* d_in, const int* in_sizes, int n_in,
                              void* d_out, int out_size, void* d_ws, size_t ws_size,
                              hipStream_t stream) {
    const int*   token_ids     = (const int*)d_in[0];
    const int*   node_lengths  = (const int*)d_in[1];
    const int*   node_sizes    = (const int*)d_in[2];
    const int*   cross_lengths = (const int*)d_in[3];
    const float* con_hidden    = (const float*)d_in[4];
    const float* emb           = (const float*)d_in[5];
    const float* W_pre         = (const float*)d_in[6];
    const float* b_pre         = (const float*)d_in[7];
    const float* W_q           = (const float*)d_in[8];
    const float* v             = (const float*)d_in[9];

    float*  out     = (float*)d_out;
    float*  hid_out = out + (size_t)TB * DD;                 // second output
    float*  q       = (float*)d_ws;                          // 16 KB
    bf16x8* wb      = (bf16x8*)((char*)d_ws + 16 * 1024);    // 64 KB packed W_pre
    unsigned short* embh = (unsigned short*)((char*)d_ws + 80 * 1024);  // 32 MB

    const size_t need = 80 * 1024 + (size_t)32000 * DD * 2;

    if (ws_size >= need) {
        preproc_kernel<<<CONV_BLKS + 128, 256, 0, stream>>>(
            emb, embh, con_hidden, W_q, q, hid_out, W_pre, wb);
        bag_kernel<true><<<TB / 4, 256, 0, stream>>>(
            token_ids, node_lengths, node_sizes, cross_lengths,
            emb, embh, b_pre, v, q, wb, out);
    } else {
        prep_kernel<<<64, 64, 0, stream>>>(con_hidden, W_q, q, hid_out);
        pack_wpre<<<64, 64, 0, stream>>>(W_pre, wb);
        bag_kernel<false><<<TB / 4, 256, 0, stream>>>(
            token_ids, node_lengths, node_sizes, cross_lengths,
            emb, nullptr, b_pre, v, q, wb, out);
    }
}

// Round 6
// 89.635 us; speedup vs baseline: 11.0976x; 1.0309x over previous
//
#include <hip/hip_runtime.h>
#include <hip/hip_bf16.h>

#define TB   8192   // B*C*N bags
#define WW   32     // words per bag
#define DD   512    // d_model
#define DKK  64     // attention dim
#define CCC  4      // max cross

#define CONV_BLKS 8000   // 32000*512/8/256

using bf16x8 = __attribute__((ext_vector_type(8))) short;
using f32x4  = __attribute__((ext_vector_type(4))) float;

__device__ __forceinline__ unsigned short f2bf(float x) {
    union { float f; unsigned u; } u;
    u.f = x;
    unsigned r = u.u + 0x7fffu + ((u.u >> 16) & 1u);
    return (unsigned short)(r >> 16);
}

__device__ __forceinline__ bf16x8 make_frag(float4 x, float4 y) {
    union { bf16x8 v; unsigned short s[8]; } u;
    u.s[0] = f2bf(x.x); u.s[1] = f2bf(x.y); u.s[2] = f2bf(x.z); u.s[3] = f2bf(x.w);
    u.s[4] = f2bf(y.x); u.s[5] = f2bf(y.y); u.s[6] = f2bf(y.z); u.s[7] = f2bf(y.w);
    return u.v;
}

// fma 8 bf16 elems (packed) into fp32 accumulators: cx[j] += s * elem[j]
__device__ __forceinline__ void bfx8_fma(float* cx, bf16x8 r, float s) {
    union { bf16x8 v; unsigned u[4]; } u; u.v = r;
    #pragma unroll
    for (int j = 0; j < 4; ++j) {
        float lo = __uint_as_float(u.u[j] << 16);
        float hi = __uint_as_float(u.u[j] & 0xffff0000u);
        cx[2 * j]     += s * lo;
        cx[2 * j + 1] += s * hi;
    }
}

// ---------------- fused preprocessing ----------------
// blocks [0, CONV_BLKS)       : emb fp32 -> bf16
// blocks [CONV_BLKS, +64)     : prep (q GEMV + hidden copy)
// blocks [CONV_BLKS+64, +128) : pack W_pre fragments
__global__ __launch_bounds__(256) void preproc_kernel(
    const float* __restrict__ emb,
    unsigned short* __restrict__ embh,
    const float* __restrict__ con_hidden,  // [64][512]
    const float* __restrict__ W_q,         // [512][64]
    float* __restrict__ qout,              // [64][64]
    float* __restrict__ hid_out,           // [64][512]
    const float* __restrict__ W_pre,       // [512][64]
    bf16x8* __restrict__ wb)               // 64 frags * 64 lanes
{
    const int blk = blockIdx.x;
    const int tid = threadIdx.x;
    if (blk < CONV_BLKS) {
        const size_t i = ((size_t)blk * 256 + tid) * 8;
        const float4* p = (const float4*)(emb + i);
        float4 a = p[0], b = p[1];
        *(bf16x8*)(embh + i) = make_frag(a, b);
    } else if (blk < CONV_BLKS + 64) {
        if (tid >= 64) return;
        const int b = blk - CONV_BLKS;
        const int k = tid;
        const float* h = con_hidden + b * DD;
        float acc = 0.0f;
        #pragma unroll 8
        for (int d = 0; d < DD; ++d) acc += h[d] * W_q[d * DKK + k];
        qout[b * DKK + k] = acc;
        const float4* src = (const float4*)h;
        float4* dst = (float4*)(hid_out + b * DD);
        for (int i = k; i < DD / 4; i += 64) dst[i] = src[i];
    } else {
        if (tid >= 64) return;
        const int fb = blk - CONV_BLKS - 64;   // ks*4 + nt
        const int ks = fb >> 2, nt = fb & 3;
        const int lr = tid & 15, lg = tid >> 4;
        union { bf16x8 v; unsigned short s[8]; } u;
        #pragma unroll
        for (int j = 0; j < 8; ++j) {
            int k = ks * 32 + lg * 8 + j;
            u.s[j] = f2bf(W_pre[k * DKK + nt * 16 + lr]);
        }
        wb[fb * 64 + tid] = u.v;
    }
}

// ---------------- main bag kernel: 8 waves/block, wb in LDS ----------------
__global__ __launch_bounds__(512) void bag_kernel(
    const int* __restrict__ token_ids,     // [8192][32]
    const int* __restrict__ node_lengths,  // [8192]
    const int* __restrict__ node_sizes,    // [256]
    const int* __restrict__ cross_lengths, // [64]
    const unsigned short* __restrict__ embh, // [32000][512] bf16, row 0 zeros
    const float* __restrict__ b_pre,       // [64]
    const float* __restrict__ v,           // [64]
    const float* __restrict__ q,           // [64][64]
    const bf16x8* __restrict__ wb,         // packed W_pre fragments (64 KB)
    float* __restrict__ out)               // [8192][512]
{
    const int tid  = threadIdx.x;
    const int wid  = tid >> 6;
    const int lane = tid & 63;
    const int t = blockIdx.x * 8 + wid;
    const int b = t >> 7, cn = t & 127, c = cn >> 5, n = cn & 31;
    const int lr = lane & 15, lg = lane >> 4;

    __shared__ bf16x8 swb[4096];   // 64 KB shared W_pre fragments

    const int L = node_lengths[t];
    const int* toks = token_ids + t * WW;

    // lane w (<32) holds masked token id of word w (emb row 0 is all-zero)
    int my_tok = 0;
    if (lane < 32 && lane < L) my_tok = toks[lane];

    // A-row tokens for the two M-tiles (words lr and 16+lr)
    const int tok0 = __shfl(my_tok, lr);
    const int tok1 = __shfl(my_tok, 16 + lr);
    const unsigned short* hp0 = embh + ((size_t)tok0 << 9) + lg * 8;
    const unsigned short* hp1 = embh + ((size_t)tok1 << 9) + lg * 8;

    bf16x8 A0[4], A1[4], Bs[2][4];
    auto loadA = [&](int ks, int sl) {
        A0[sl] = *(const bf16x8*)(hp0 + ks * 32);
        A1[sl] = *(const bf16x8*)(hp1 + ks * 32);
    };
    auto loadB = [&](int ks, int sl) {
        #pragma unroll
        for (int nt = 0; nt < 4; ++nt)
            Bs[sl][nt] = swb[(ks * 4 + nt) * 64 + lane];
    };

    // issue gather prologue BEFORE the LDS fill so it hides under the fill
    loadA(0, 0); loadA(1, 1); loadA(2, 2); loadA(3, 3);
    asm volatile("" ::: "memory");

    // cooperative fill of wb -> LDS (4096 x 16B, 8 iters/thread)
    #pragma unroll
    for (int i = tid; i < 4096; i += 512) swb[i] = wb[i];
    __syncthreads();            // the ONLY block-wide barrier

    f32x4 acc[2][4];
    #pragma unroll
    for (int mt = 0; mt < 2; ++mt)
        #pragma unroll
        for (int nt = 0; nt < 4; ++nt)
            acc[mt][nt] = (f32x4){0.f, 0.f, 0.f, 0.f};

    loadB(0, 0);
    asm volatile("" ::: "memory");

    // ---- pre = bag @ W_pre via MFMA: A 4-deep (global), B 2-deep (LDS) ----
    #pragma unroll
    for (int ks = 0; ks < 16; ++ks) {
        bf16x8 a0 = A0[ks & 3], a1 = A1[ks & 3];   // consume before slot reuse
        if (ks + 4 < 16) loadA(ks + 4, (ks + 4) & 3);
        if (ks + 1 < 16) loadB(ks + 1, (ks + 1) & 1);
        asm volatile("" ::: "memory");             // loads cannot sink past here
        const int bs = ks & 1;
        acc[0][0] = __builtin_amdgcn_mfma_f32_16x16x32_bf16(a0, Bs[bs][0], acc[0][0], 0, 0, 0);
        acc[0][1] = __builtin_amdgcn_mfma_f32_16x16x32_bf16(a0, Bs[bs][1], acc[0][1], 0, 0, 0);
        acc[0][2] = __builtin_amdgcn_mfma_f32_16x16x32_bf16(a0, Bs[bs][2], acc[0][2], 0, 0, 0);
        acc[0][3] = __builtin_amdgcn_mfma_f32_16x16x32_bf16(a0, Bs[bs][3], acc[0][3], 0, 0, 0);
        acc[1][0] = __builtin_amdgcn_mfma_f32_16x16x32_bf16(a1, Bs[bs][0], acc[1][0], 0, 0, 0);
        acc[1][1] = __builtin_amdgcn_mfma_f32_16x16x32_bf16(a1, Bs[bs][1], acc[1][1], 0, 0, 0);
        acc[1][2] = __builtin_amdgcn_mfma_f32_16x16x32_bf16(a1, Bs[bs][2], acc[1][2], 0, 0, 0);
        acc[1][3] = __builtin_amdgcn_mfma_f32_16x16x32_bf16(a1, Bs[bs][3], acc[1][3], 0, 0, 0);
    }

    // ---- energy: e[w] = sum_k tanh(pre + b_pre + q) * v  (all in registers) ----
    // C layout: col = nt*16 + lr ; row(word) = mt*16 + lg*4 + r
    float qb[4], vv[4];
    #pragma unroll
    for (int nt = 0; nt < 4; ++nt) {
        int cidx = nt * 16 + lr;
        qb[nt] = q[b * DKK + cidx] + b_pre[cidx];
        vv[nt] = v[cidx];
    }
    float ev[8];   // ev[mt*4+r] = e[mt*16 + lg*4 + r], replicated across lr
    #pragma unroll
    for (int mt = 0; mt < 2; ++mt) {
        #pragma unroll
        for (int r = 0; r < 4; ++r) {
            float s = 0.0f;
            #pragma unroll
            for (int nt = 0; nt < 4; ++nt) {
                float pre = acc[mt][nt][r] + qb[nt];
                float ez = __expf(2.0f * pre);                 // tanh via exp
                float th = 1.0f - 2.0f * __builtin_amdgcn_rcpf(ez + 1.0f);
                s += th * vv[nt];
            }
            s += __shfl_xor(s, 1);
            s += __shfl_xor(s, 2);
            s += __shfl_xor(s, 4);
            s += __shfl_xor(s, 8);   // now every lane in the lg-group has e[w]
            ev[mt * 4 + r] = s;
        }
    }

    // ---- softmax over 32 word slots, wave-local (reduce across lg groups) ----
    float mx = ev[0];
    #pragma unroll
    for (int j = 1; j < 8; ++j) mx = fmaxf(mx, ev[j]);
    mx = fmaxf(mx, __shfl_xor(mx, 16));
    mx = fmaxf(mx, __shfl_xor(mx, 32));
    float sc[8], sm = 0.0f;
    #pragma unroll
    for (int j = 0; j < 8; ++j) { sc[j] = __expf(ev[j] - mx); sm += sc[j]; }
    sm += __shfl_xor(sm, 16);
    sm += __shfl_xor(sm, 32);
    const float inv = 1.0f / sm;
    #pragma unroll
    for (int j = 0; j < 8; ++j) sc[j] *= inv;

    // ---- context: lane owns 8 consecutive d's; pipelined gather (L2-hot) ----
    const int d0 = lane * 8;
    float cx[8];
    #pragma unroll
    for (int j = 0; j < 8; ++j) cx[j] = 0.0f;

    bf16x8 R[4];
    auto cissue = [&](int w, int sl) {
        int tk = __shfl(my_tok, w);
        R[sl] = *(const bf16x8*)(embh + ((size_t)tk << 9) + d0);
    };
    cissue(0, 0); cissue(1, 1); cissue(2, 2); cissue(3, 3);
    asm volatile("" ::: "memory");
    #pragma unroll
    for (int w = 0; w < WW; ++w) {
        bf16x8 r = R[w & 3];                      // consume before slot reuse
        // score s[w]: held as element (w>>4)*4+(w&3) in lanes with lg==(w>>2)&3
        float s = __shfl(sc[(w >> 4) * 4 + (w & 3)], ((w >> 2) & 3) * 16);
        if (w + 4 < WW) cissue(w + 4, (w + 4) & 3);
        asm volatile("" ::: "memory");
        bfx8_fma(cx, r, s);
    }

    const bool outmask = (n < node_sizes[b * CCC + c]) && (c < cross_lengths[b]);
    if (!outmask) {
        #pragma unroll
        for (int j = 0; j < 8; ++j) cx[j] = 0.0f;
    }
    float4* op = (float4*)(out + (size_t)t * DD + d0);
    op[0] = float4{cx[0], cx[1], cx[2], cx[3]};
    op[1] = float4{cx[4], cx[5], cx[6], cx[7]};
}

// ---------------- fp32 fallback (ws too small; not expected in practice) ----
__global__ __launch_bounds__(64) void prep_kernel(
    const float* __restrict__ con_hidden, const float* __restrict__ W_q,
    float* __restrict__ qout, float* __restrict__ hid_out)
{
    const int b = blockIdx.x;
    const int k = threadIdx.x;
    const float* h = con_hidden + b * DD;
    float acc = 0.0f;
    #pragma unroll 8
    for (int d = 0; d < DD; ++d) acc += h[d] * W_q[d * DKK + k];
    qout[b * DKK + k] = acc;
    const float4* src = (const float4*)h;
    float4* dst = (float4*)(hid_out + b * DD);
    for (int i = k; i < DD / 4; i += 64) dst[i] = src[i];
}

__global__ __launch_bounds__(64) void pack_wpre(
    const float* __restrict__ W_pre, bf16x8* __restrict__ wb)
{
    const int blk = blockIdx.x;
    const int ks = blk >> 2, nt = blk & 3;
    const int l  = threadIdx.x;
    const int lr = l & 15, lg = l >> 4;
    union { bf16x8 v; unsigned short s[8]; } u;
    #pragma unroll
    for (int j = 0; j < 8; ++j) {
        int k = ks * 32 + lg * 8 + j;
        u.s[j] = f2bf(W_pre[k * DKK + nt * 16 + lr]);
    }
    wb[blk * 64 + l] = u.v;
}

__global__ __launch_bounds__(256) void bag_kernel_f32(
    const int* __restrict__ token_ids, const int* __restrict__ node_lengths,
    const int* __restrict__ node_sizes, const int* __restrict__ cross_lengths,
    const float* __restrict__ embf, const float* __restrict__ b_pre,
    const float* __restrict__ v, const float* __restrict__ q,
    const bf16x8* __restrict__ wb, float* __restrict__ out)
{
    const int wid  = threadIdx.x >> 6;
    const int lane = threadIdx.x & 63;
    const int t = blockIdx.x * 4 + wid;
    const int b = t >> 7, cn = t & 127, c = cn >> 5, n = cn & 31;
    const int lr = lane & 15, lg = lane >> 4;

    const int L = node_lengths[t];
    const int* toks = token_ids + t * WW;
    int my_tok = 0;
    if (lane < 32 && lane < L) my_tok = toks[lane];
    const int tok0 = __shfl(my_tok, lr);
    const int tok1 = __shfl(my_tok, 16 + lr);
    const float* fp0 = embf + ((size_t)tok0 << 9) + lg * 8;
    const float* fp1 = embf + ((size_t)tok1 << 9) + lg * 8;

    f32x4 acc[2][4];
    #pragma unroll
    for (int mt = 0; mt < 2; ++mt)
        #pragma unroll
        for (int nt = 0; nt < 4; ++nt)
            acc[mt][nt] = (f32x4){0.f, 0.f, 0.f, 0.f};

    #pragma unroll 4
    for (int ks = 0; ks < 16; ++ks) {
        const float4* a0p = (const float4*)(fp0 + ks * 32);
        const float4* a1p = (const float4*)(fp1 + ks * 32);
        bf16x8 a0 = make_frag(a0p[0], a0p[1]);
        bf16x8 a1 = make_frag(a1p[0], a1p[1]);
        #pragma unroll
        for (int nt = 0; nt < 4; ++nt) {
            bf16x8 bb = wb[(ks * 4 + nt) * 64 + lane];
            acc[0][nt] = __builtin_amdgcn_mfma_f32_16x16x32_bf16(a0, bb, acc[0][nt], 0, 0, 0);
            acc[1][nt] = __builtin_amdgcn_mfma_f32_16x16x32_bf16(a1, bb, acc[1][nt], 0, 0, 0);
        }
    }

    float qb[4], vv[4];
    #pragma unroll
    for (int nt = 0; nt < 4; ++nt) {
        int cidx = nt * 16 + lr;
        qb[nt] = q[b * DKK + cidx] + b_pre[cidx];
        vv[nt] = v[cidx];
    }
    float ev[8];
    #pragma unroll
    for (int mt = 0; mt < 2; ++mt) {
        #pragma unroll
        for (int r = 0; r < 4; ++r) {
            float s = 0.0f;
            #pragma unroll
            for (int nt = 0; nt < 4; ++nt) {
                float pre = acc[mt][nt][r] + qb[nt];
                float ez = __expf(2.0f * pre);
                float th = 1.0f - 2.0f * __builtin_amdgcn_rcpf(ez + 1.0f);
                s += th * vv[nt];
            }
            s += __shfl_xor(s, 1); s += __shfl_xor(s, 2);
            s += __shfl_xor(s, 4); s += __shfl_xor(s, 8);
            ev[mt * 4 + r] = s;
        }
    }
    float mx = ev[0];
    #pragma unroll
    for (int j = 1; j < 8; ++j) mx = fmaxf(mx, ev[j]);
    mx = fmaxf(mx, __shfl_xor(mx, 16));
    mx = fmaxf(mx, __shfl_xor(mx, 32));
    float sc[8], sm = 0.0f;
    #pragma unroll
    for (int j = 0; j < 8; ++j) { sc[j] = __expf(ev[j] - mx); sm += sc[j]; }
    sm += __shfl_xor(sm, 16); sm += __shfl_xor(sm, 32);
    const float inv = 1.0f / sm;
    #pragma unroll
    for (int j = 0; j < 8; ++j) sc[j] *= inv;

    const int d0 = lane * 8;
    float cx[8];
    #pragma unroll
    for (int j = 0; j < 8; ++j) cx[j] = 0.0f;
    #pragma unroll
    for (int w = 0; w < WW; ++w) {
        int tk = __shfl(my_tok, w);
        float s = __shfl(sc[(w >> 4) * 4 + (w & 3)], ((w >> 2) & 3) * 16);
        const float4* pr = (const float4*)(embf + ((size_t)tk << 9) + d0);
        float4 x0 = pr[0], x1 = pr[1];
        cx[0] += s * x0.x; cx[1] += s * x0.y; cx[2] += s * x0.z; cx[3] += s * x0.w;
        cx[4] += s * x1.x; cx[5] += s * x1.y; cx[6] += s * x1.z; cx[7] += s * x1.w;
    }
    const bool outmask = (n < node_sizes[b * CCC + c]) && (c < cross_lengths[b]);
    if (!outmask) {
        #pragma unroll
        for (int j = 0; j < 8; ++j) cx[j] = 0.0f;
    }
    float4* op = (float4*)(out + (size_t)t * DD + d0);
    op[0] = float4{cx[0], cx[1], cx[2], cx[3]};
    op[1] = float4{cx[4], cx[5], cx[6], cx[7]};
}

extern "C" void kernel_launch(void* const* d_in, const int* in_sizes, int n_in,
                              void* d_out, int out_size, void* d_ws, size_t ws_size,
                              hipStream_t stream) {
    const int*   token_ids     = (const int*)d_in[0];
    const int*   node_lengths  = (const int*)d_in[1];
    const int*   node_sizes    = (const int*)d_in[2];
    const int*   cross_lengths = (const int*)d_in[3];
    const float* con_hidden    = (const float*)d_in[4];
    const float* emb           = (const float*)d_in[5];
    const float* W_pre         = (const float*)d_in[6];
    const float* b_pre         = (const float*)d_in[7];
    const float* W_q           = (const float*)d_in[8];
    const float* v             = (const float*)d_in[9];

    float*  out     = (float*)d_out;
    float*  hid_out = out + (size_t)TB * DD;                 // second output
    float*  q       = (float*)d_ws;                          // 16 KB
    bf16x8* wb      = (bf16x8*)((char*)d_ws + 16 * 1024);    // 64 KB packed W_pre
    unsigned short* embh = (unsigned short*)((char*)d_ws + 80 * 1024);  // 32 MB

    const size_t need = 80 * 1024 + (size_t)32000 * DD * 2;

    if (ws_size >= need) {
        preproc_kernel<<<CONV_BLKS + 128, 256, 0, stream>>>(
            emb, embh, con_hidden, W_q, q, hid_out, W_pre, wb);
        bag_kernel<<<TB / 8, 512, 0, stream>>>(
            token_ids, node_lengths, node_sizes, cross_lengths,
            embh, b_pre, v, q, wb, out);
    } else {
        prep_kernel<<<64, 64, 0, stream>>>(con_hidden, W_q, q, hid_out);
        pack_wpre<<<64, 64, 0, stream>>>(W_pre, wb);
        bag_kernel_f32<<<TB / 4, 256, 0, stream>>>(
            token_ids, node_lengths, node_sizes, cross_lengths,
            emb, b_pre, v, q, wb, out);
    }
}